// Round 4
// baseline (10639.780 us; speedup 1.0000x reference)
//
#include <hip/hip_runtime.h>

typedef float v4 __attribute__((ext_vector_type(4)));
typedef unsigned short u16;
typedef unsigned int u32;

#define DEVI __device__ __forceinline__

namespace {

constexpr int B = 64, C = 64, NPT = 500, T0 = 13, SC = 256, EC = 512, PR = 12;
constexpr size_t SLOT = (size_t)B * C * NPT;  // 2,048,000 elems per time slice

// byte offsets in d_ws
constexpr size_t OB_X   = 0;                         // bf16 [13][b][c][n]   53,248,000 B
constexpr size_t OB_XAS = OB_X + 13 * SLOT * 2;      // f32  [b][c][n]        8,192,000 B
constexpr size_t OB_H1  = 0;                         // bf16 [512][b*n] (overlays X after loop)
constexpr size_t OB_SK  = OB_XAS + SLOT * 4;         // f32  [256][b*n]      32,768,000 B
constexpr size_t OB_ST  = OB_SK + (size_t)SC * B * NPT * 4;  // f64 [128]        1,024 B
constexpr size_t OB_WF  = OB_ST + 1024;              // f32 [l][tap][c][cp]     262,144 B
constexpr size_t OB_WG  = OB_WF + 65536 * 4;         // f32                     262,144 B
constexpr size_t OB_SWT = OB_WG + 65536 * 4;         // f32 [l][c][o256]        524,288 B
constexpr size_t OB_GWT = OB_SWT + 131072 * 4;       // f32 [l][kc][o]          262,144 B
constexpr size_t OB_W1T = OB_GWT + 65536 * 4;        // f32 [o256][e512]        524,288 B
constexpr size_t WS_NEED = OB_W1T + 131072 * 4;      // = 96,044,032 B (~91.6 MiB)

DEVI float sigm(float x) { return 1.f / (1.f + expf(-x)); }
DEVI float bf2f(u16 u) { u32 x = ((u32)u) << 16; float f; __builtin_memcpy(&f, &x, 4); return f; }
DEVI u16 f2bf(float f) { u32 x; __builtin_memcpy(&x, &f, 4); return (u16)((x + 0x7FFF + ((x >> 16) & 1)) >> 16); }

// ---------------- debug: report ws_size (MB) through the output ----------------
__global__ void k_debug_ws(float* __restrict__ out, float val) {
  int i = blockIdx.x * 256 + threadIdx.x;
  if (i < B * PR * NPT) out[i] = val;
}

// ---------------- weight repack ----------------
__global__ void k_prep(const float* __restrict__ fw, const float* __restrict__ gw,
                       const float* __restrict__ sw, const float* __restrict__ gcw,
                       const float* __restrict__ o1w,
                       float* __restrict__ WF, float* __restrict__ WG,
                       float* __restrict__ SWT, float* __restrict__ GWT,
                       float* __restrict__ W1T) {
  int i = blockIdx.x * 256 + threadIdx.x;
  if (i < 65536) {  // [l][tap][c][cp] <- fw[((l*64+cp)*64+c)*2+tap]
    int cp = i & 63, c = (i >> 6) & 63, tap = (i >> 12) & 1, l = i >> 13;
    int g = ((l * 64 + cp) * 64 + c) * 2 + tap;
    WF[i] = fw[g];
    WG[i] = gw[g];
  }
  int j = i - 131072;
  if (j >= 0 && j < 131072) {  // [l][c][o] <- sw[(l*256+o)*64+c]
    int o = j & 255, cl = (j >> 8) & 63, l = j >> 14;
    SWT[j] = sw[(l * 256 + o) * 64 + cl];
  }
  int k2 = i - 262144;
  if (k2 >= 0 && k2 < 65536) {  // [l][kc][o] <- gcw[(l*64+o)*128+kc]
    int o = k2 & 63, kc = (k2 >> 6) & 127, l = k2 >> 13;
    GWT[k2] = gcw[(l * 64 + o) * 128 + kc];
  }
  int m = i - 327680;
  if (m >= 0 && m < 131072) {  // [o][e] <- o1w[e*256+o]
    int e = m & 511, o = m >> 9;
    W1T[m] = o1w[e * 256 + o];
  }
}

// ---------------- enter: [B,12,N,2] -> Xbf[t][b][c][n], t=0 is left-pad ----------------
__global__ void k_enter(const float* __restrict__ in, const float* __restrict__ ew,
                        const float* __restrict__ eb, u16* __restrict__ X) {
  size_t idx = (size_t)blockIdx.x * 256 + threadIdx.x;
  if (idx >= 13 * SLOT) return;
  int t = (int)(idx / SLOT);
  size_t r = idx % SLOT;
  int n = (int)(r % NPT);
  int c = (int)((r / NPT) % C);
  int b = (int)(r / ((size_t)NPT * C));
  float v = eb[c];
  if (t > 0) {
    const float* ip = in + (((size_t)b * 12 + (t - 1)) * NPT + n) * 2;
    v += ew[c * 2] * ip[0] + ew[c * 2 + 1] * ip[1];
  }
  X[idx] = f2bf(v);
}

// ---------------- gated conv for ONE time slice t: XAS[b][c'][n] ----------------
// grid (8, B) block (16,16)
__global__ __launch_bounds__(256) void k_gatedconv(
    const u16* __restrict__ X, float* __restrict__ XAS,
    const float* __restrict__ WFl, const float* __restrict__ bf,
    const float* __restrict__ WGl, const float* __restrict__ bg,
    int t, int d) {
  __shared__ __align__(16) float wfs[8192];  // [tap][c][cp]
  __shared__ __align__(16) float wgs[8192];
  __shared__ __align__(16) float xs[2048];   // [tap][cc16][n64]
  const int tx = threadIdx.x, ty = threadIdx.y;
  const int tid = ty * 16 + tx;
  const int n0 = blockIdx.x * 64;
  const int b = blockIdx.y;
  for (int i = tid; i < 8192; i += 256) {
    wfs[i] = WFl[i];
    wgs[i] = WGl[i];
  }
  v4 f[4] = {}, g[4] = {};
  for (int c0 = 0; c0 < 64; c0 += 16) {
    __syncthreads();
    for (int i = tid; i < 2048; i += 256) {
      int nn = i & 63, cc = (i >> 6) & 15, tap = i >> 10;
      int n = n0 + nn;
      xs[i] = (n < NPT)
          ? bf2f(X[(size_t)(t + tap * d) * SLOT + ((size_t)b * C + c0 + cc) * NPT + n])
          : 0.f;
    }
    __syncthreads();
#pragma unroll
    for (int cc = 0; cc < 16; ++cc) {
      v4 xv0 = *(const v4*)&xs[cc * 64 + tx * 4];
      v4 xv1 = *(const v4*)&xs[1024 + cc * 64 + tx * 4];
      int c = c0 + cc;
      v4 wf0 = *(const v4*)&wfs[c * 64 + ty * 4];
      v4 wf1 = *(const v4*)&wfs[4096 + c * 64 + ty * 4];
      v4 wg0 = *(const v4*)&wgs[c * 64 + ty * 4];
      v4 wg1 = *(const v4*)&wgs[4096 + c * 64 + ty * 4];
#pragma unroll
      for (int r = 0; r < 4; ++r) {
        f[r] += wf0[r] * xv0 + wf1[r] * xv1;
        g[r] += wg0[r] * xv0 + wg1[r] * xv1;
      }
    }
  }
  const int cp = ty * 4;
  const int n = n0 + tx * 4;
#pragma unroll
  for (int r = 0; r < 4; ++r) {
    float fb = bf[cp + r], gb2 = bg[cp + r];
    size_t ob = ((size_t)b * C + cp + r) * NPT;
#pragma unroll
    for (int q = 0; q < 4; ++q) {
      if (n + q < NPT) {
        float F = f[r][q] + fb, G = g[r][q] + gb2;
        XAS[ob + n + q] = tanhf(F) * sigm(G);
      }
    }
  }
}

// ---------------- skip GEMM on the layer's LAST slice (XAS) ----------------
// SK[o][b][n] (+)= sb[o] + sum_c sw[o][c]*XAS[b][c][n] ; grid (8, 4, B)
__global__ __launch_bounds__(256) void k_skip(
    const float* __restrict__ XAS, float* __restrict__ SK,
    const float* __restrict__ SWTl, const float* __restrict__ sb, int add) {
  __shared__ __align__(16) float wsm[4096];  // [c][o64]
  __shared__ __align__(16) float xsm[1024];  // [cc16][n64]
  const int tx = threadIdx.x, ty = threadIdx.y;
  const int tid = ty * 16 + tx;
  const int n0 = blockIdx.x * 64, o0 = blockIdx.y * 64, b = blockIdx.z;
  for (int i = tid; i < 4096; i += 256) {
    int oo = i & 63, c = i >> 6;
    wsm[i] = SWTl[c * 256 + o0 + oo];
  }
  v4 acc[4] = {};
  const size_t xbase = (size_t)b * C * NPT;
  for (int c0 = 0; c0 < 64; c0 += 16) {
    __syncthreads();
    for (int i = tid; i < 1024; i += 256) {
      int nn = i & 63, cc = i >> 6;
      int n = n0 + nn;
      xsm[i] = (n < NPT) ? XAS[xbase + (size_t)(c0 + cc) * NPT + n] : 0.f;
    }
    __syncthreads();
#pragma unroll
    for (int cc = 0; cc < 16; ++cc) {
      v4 xv = *(const v4*)&xsm[cc * 64 + tx * 4];
      v4 wv = *(const v4*)&wsm[(c0 + cc) * 64 + ty * 4];
#pragma unroll
      for (int r = 0; r < 4; ++r) acc[r] += wv[r] * xv;
    }
  }
#pragma unroll
  for (int r = 0; r < 4; ++r) {
    int o = o0 + ty * 4 + r;
    float bb = sb[o];
    size_t ob = (size_t)o * (B * NPT) + (size_t)b * NPT + n0 + tx * 4;
#pragma unroll
    for (int q = 0; q < 4; ++q) {
      int n = n0 + tx * 4 + q;
      if (n < NPT) {
        float v = acc[r][q] + bb;
        if (add) SK[ob + q] += v; else SK[ob + q] = v;
      }
    }
  }
}

// ---------------- diffusion + mix + residual for ONE slice; writes X slot t (bf16) ----------------
// grid (8, B) block (16,16)
__global__ __launch_bounds__(256) void k_diffmix(
    const float* __restrict__ XAS, u16* __restrict__ X,
    const float* __restrict__ Sup,
    const float* __restrict__ GWTl, const float* __restrict__ gb,
    int t, int d) {
  __shared__ __align__(16) float sm[18392];
  const int tx = threadIdx.x, ty = threadIdx.y;
  const int tid = ty * 16 + tx;
  const int n0 = blockIdx.x * 64, b = blockIdx.y;
  float* xs = sm;          // [50][68] (m, c)
  float* s0 = sm + 3400;   // [50][68] (m, n)
  float* s1 = sm + 6800;
  v4 h0[4] = {}, h1[4] = {};
  const size_t xbase = (size_t)b * C * NPT;
  for (int m0 = 0; m0 < NPT; m0 += 50) {
    __syncthreads();
    for (int i = tid; i < 3200; i += 256) {
      int mm = i % 50, cc = i / 50;
      xs[mm * 68 + cc] = XAS[xbase + (size_t)cc * NPT + m0 + mm];
    }
    for (int i = tid; i < 3200; i += 256) {
      int mm = i % 50, nn = i / 50;
      int n = n0 + nn;
      float a0 = 0.f, a1 = 0.f;
      if (n < NPT) {
        a0 = Sup[(size_t)n * NPT + m0 + mm];
        a1 = Sup[(size_t)(NPT + n) * NPT + m0 + mm];
      }
      s0[mm * 68 + nn] = a0;
      s1[mm * 68 + nn] = a1;
    }
    __syncthreads();
#pragma unroll 10
    for (int mm = 0; mm < 50; ++mm) {
      v4 xv = *(const v4*)&xs[mm * 68 + ty * 4];
      v4 a0 = *(const v4*)&s0[mm * 68 + tx * 4];
      v4 a1 = *(const v4*)&s1[mm * 68 + tx * 4];
#pragma unroll
      for (int r = 0; r < 4; ++r) {
        h0[r] += xv[r] * a0;
        h1[r] += xv[r] * a1;
      }
    }
  }
  // epilogue: XG[o][n] = gb[o] + sum_c (W0[o][c]H0[c][n] + W1[o][c]H1[c][n]) + x[t+d]
  __syncthreads();
  float* hs0 = sm;          // [64][68]
  float* hs1 = sm + 4352;
  float* wt  = sm + 10200;  // [128][64]  (kc, o)
#pragma unroll
  for (int r = 0; r < 4; ++r)
#pragma unroll
    for (int q = 0; q < 4; ++q) {
      hs0[(ty * 4 + r) * 68 + tx * 4 + q] = h0[r][q];
      hs1[(ty * 4 + r) * 68 + tx * 4 + q] = h1[r][q];
    }
  for (int i = tid; i < 8192; i += 256) wt[i] = GWTl[i];
  __syncthreads();
  v4 acc[4] = {};
#pragma unroll 8
  for (int c = 0; c < 64; ++c) {
    v4 hv0 = *(const v4*)&hs0[c * 68 + tx * 4];
    v4 hv1 = *(const v4*)&hs1[c * 68 + tx * 4];
    v4 w0 = *(const v4*)&wt[c * 64 + ty * 4];
    v4 w1 = *(const v4*)&wt[(64 + c) * 64 + ty * 4];
#pragma unroll
    for (int r = 0; r < 4; ++r) acc[r] += w0[r] * hv0 + w1[r] * hv1;
  }
#pragma unroll
  for (int r = 0; r < 4; ++r) {
    int o = ty * 4 + r;
    float bias = gb[o];
    size_t orow = (size_t)t * SLOT + ((size_t)b * C + o) * NPT + n0 + tx * 4;
    size_t rrow = (size_t)(t + d) * SLOT + ((size_t)b * C + o) * NPT + n0 + tx * 4;
#pragma unroll
    for (int q = 0; q < 4; ++q) {
      int n = n0 + tx * 4 + q;
      if (n < NPT) X[orow + q] = f2bf(acc[r][q] + bias + bf2f(X[rrow + q]));
    }
  }
}

__global__ void k_zero(double* __restrict__ p) {
  if (threadIdx.x < 128) p[threadIdx.x] = 0.0;
}

// ---------------- BN pass 1: per-channel sum (f64) over slots 0..Tp-1 ----------------
__global__ void k_bnsum(const u16* __restrict__ X, double* __restrict__ st, int Tp) {
  int c = blockIdx.y;
  int per = Tp * B * NPT;
  double s = 0.0;
  for (int p = blockIdx.x * 256 + threadIdx.x; p < per; p += 8 * 256) {
    int t = p / (B * NPT);
    int r = p - t * (B * NPT);
    int b = r / NPT, n = r - b * NPT;
    s += (double)bf2f(X[(size_t)t * SLOT + ((size_t)b * C + c) * NPT + n]);
  }
  for (int off = 32; off; off >>= 1) s += __shfl_down(s, off, 64);
  if ((threadIdx.x & 63) == 0) atomicAdd(&st[c], s);
}

// ---------------- BN pass 2: per-channel sum of (x-mean)^2 ----------------
__global__ void k_bnvar(const u16* __restrict__ X, double* __restrict__ st, int Tp) {
  int c = blockIdx.y;
  int per = Tp * B * NPT;
  double mean = st[c] / (double)per;
  double s = 0.0;
  for (int p = blockIdx.x * 256 + threadIdx.x; p < per; p += 8 * 256) {
    int t = p / (B * NPT);
    int r = p - t * (B * NPT);
    int b = r / NPT, n = r - b * NPT;
    double d2 = (double)bf2f(X[(size_t)t * SLOT + ((size_t)b * C + c) * NPT + n]) - mean;
    s += d2 * d2;
  }
  for (int off = 32; off; off >>= 1) s += __shfl_down(s, off, 64);
  if ((threadIdx.x & 63) == 0) atomicAdd(&st[C + c], s);
}

// ---------------- BN apply in place on slots 0..Tp-1 ----------------
__global__ void k_bnapply(u16* __restrict__ X, const double* __restrict__ st,
                          const float* __restrict__ gamma, const float* __restrict__ beta,
                          int Tp) {
  size_t g = ((size_t)blockIdx.x * 256 + threadIdx.x) * 4;
  size_t r = g % SLOT;
  int c = (int)((r / NPT) % C);
  double cnt = (double)Tp * (double)(B * NPT);
  float mean = (float)(st[c] / cnt);
  float var = (float)(st[C + c] / cnt);
  float scl = gamma[c] * rsqrtf(var + 1e-5f);
  float sh = beta[c];
  ushort4 u = *(const ushort4*)&X[g];
  ushort4 o;
  o.x = f2bf((bf2f(u.x) - mean) * scl + sh);
  o.y = f2bf((bf2f(u.y) - mean) * scl + sh);
  o.z = f2bf((bf2f(u.z) - mean) * scl + sh);
  o.w = f2bf((bf2f(u.w) - mean) * scl + sh);
  *(ushort4*)&X[g] = o;
}

// ---------------- head 1: H1[e][p] = relu(b1 + W1 * relu(SK)) (bf16 out) ----------------
__global__ __launch_bounds__(256) void k_out1(const float* __restrict__ SK,
                                              const float* __restrict__ W1T,
                                              const float* __restrict__ b1,
                                              u16* __restrict__ H1) {
  __shared__ __align__(16) float ssm[32 * 64];
  __shared__ __align__(16) float wsm[32 * 64];
  const int tx = threadIdx.x, ty = threadIdx.y;
  const int tid = ty * 16 + tx;
  const int p0 = blockIdx.x * 64, e0 = blockIdx.y * 64;
  v4 acc[4] = {};
  for (int o0 = 0; o0 < SC; o0 += 32) {
    __syncthreads();
    for (int i = tid; i < 2048; i += 256) {
      int pp = i & 63, kk = i >> 6;
      ssm[i] = fmaxf(SK[(size_t)(o0 + kk) * (B * NPT) + p0 + pp], 0.f);
      wsm[i] = W1T[(size_t)(o0 + kk) * 512 + e0 + pp];
    }
    __syncthreads();
#pragma unroll
    for (int kk = 0; kk < 32; ++kk) {
      v4 sv = *(const v4*)&ssm[kk * 64 + tx * 4];
      v4 wv = *(const v4*)&wsm[kk * 64 + ty * 4];
#pragma unroll
      for (int r = 0; r < 4; ++r) acc[r] += wv[r] * sv;
    }
  }
#pragma unroll
  for (int r = 0; r < 4; ++r) {
    int e = e0 + ty * 4 + r;
    float bb = b1[e];
    size_t ob = (size_t)e * (B * NPT) + p0 + tx * 4;
#pragma unroll
    for (int q = 0; q < 4; ++q) H1[ob + q] = f2bf(fmaxf(acc[r][q] + bb, 0.f));
  }
}

// ---------------- head 2: out[(b*12+p12)*500+n] = b2 + W2 * H1 ----------------
__global__ __launch_bounds__(256) void k_out2(const u16* __restrict__ H1,
                                              const float* __restrict__ W2,
                                              const float* __restrict__ b2,
                                              float* __restrict__ out) {
  int idx = blockIdx.x * 256 + threadIdx.x;
  if (idx >= B * PR * NPT) return;
  int n = idx % NPT;
  int p12 = (idx / NPT) % PR;
  int b = idx / (NPT * PR);
  size_t p = (size_t)b * NPT + n;
  const float* w = W2 + p12 * EC;
  float acc = b2[p12];
  for (int e = 0; e < EC; e += 4) {
    acc += w[e] * bf2f(H1[(size_t)e * (B * NPT) + p])
         + w[e + 1] * bf2f(H1[(size_t)(e + 1) * (B * NPT) + p])
         + w[e + 2] * bf2f(H1[(size_t)(e + 2) * (B * NPT) + p])
         + w[e + 3] * bf2f(H1[(size_t)(e + 3) * (B * NPT) + p]);
  }
  out[idx] = acc;
}

}  // namespace

extern "C" void kernel_launch(void* const* d_in, const int* in_sizes, int n_in,
                              void* d_out, int out_size, void* d_ws, size_t ws_size,
                              hipStream_t stream) {
  const float* inputs  = (const float*)d_in[0];
  const float* sup     = (const float*)d_in[1];
  const float* enter_w = (const float*)d_in[2];
  const float* enter_b = (const float*)d_in[3];
  const float* filt_w  = (const float*)d_in[4];
  const float* filt_b  = (const float*)d_in[5];
  const float* gate_w  = (const float*)d_in[6];
  const float* gate_b  = (const float*)d_in[7];
  const float* gconv_w = (const float*)d_in[8];
  const float* gconv_b = (const float*)d_in[9];
  const float* skip_w  = (const float*)d_in[10];
  const float* skip_b  = (const float*)d_in[11];
  const float* bn_g    = (const float*)d_in[12];
  const float* bn_b    = (const float*)d_in[13];
  const float* o1w     = (const float*)d_in[14];
  const float* o1b     = (const float*)d_in[15];
  const float* o2w     = (const float*)d_in[16];
  const float* o2b     = (const float*)d_in[17];
  (void)in_sizes; (void)n_in; (void)out_size;

  if (ws_size < WS_NEED) {
    // Debug channel: report available workspace (in MB) through the output.
    k_debug_ws<<<1500, 256, 0, stream>>>((float*)d_out, (float)(ws_size >> 20));
    return;
  }

  char* base = (char*)d_ws;
  u16*    X   = (u16*)(base + OB_X);
  float*  XAS = (float*)(base + OB_XAS);
  u16*    H1  = (u16*)(base + OB_H1);
  float*  SK  = (float*)(base + OB_SK);
  double* ST  = (double*)(base + OB_ST);
  float*  WF  = (float*)(base + OB_WF);
  float*  WG  = (float*)(base + OB_WG);
  float*  SWT = (float*)(base + OB_SWT);
  float*  GWT = (float*)(base + OB_GWT);
  float*  W1T = (float*)(base + OB_W1T);

  k_prep<<<1792, 256, 0, stream>>>(filt_w, gate_w, skip_w, gconv_w, o1w,
                                   WF, WG, SWT, GWT, W1T);
  k_enter<<<(int)((13 * SLOT) / 256), 256, 0, stream>>>(inputs, enter_w, enter_b, X);

  static const int dils[8] = {1, 2, 1, 2, 1, 2, 1, 2};
  int T = T0;
  for (int l = 0; l < 8; ++l) {
    int d = dils[l];
    int Tp = T - d;
    for (int t = 0; t < Tp; ++t) {
      k_gatedconv<<<dim3(8, B), dim3(16, 16), 0, stream>>>(
          X, XAS, WF + l * 8192, filt_b + l * 64, WG + l * 8192, gate_b + l * 64, t, d);
      if (t == Tp - 1)
        k_skip<<<dim3(8, 4, B), dim3(16, 16), 0, stream>>>(
            XAS, SK, SWT + l * 16384, skip_b + l * 256, l > 0 ? 1 : 0);
      k_diffmix<<<dim3(8, B), dim3(16, 16), 0, stream>>>(
          XAS, X, sup, GWT + l * 8192, gconv_b + l * 64, t, d);
    }
    k_zero<<<1, 128, 0, stream>>>(ST);
    k_bnsum<<<dim3(8, C), 256, 0, stream>>>(X, ST, Tp);
    k_bnvar<<<dim3(8, C), 256, 0, stream>>>(X, ST, Tp);
    k_bnapply<<<Tp * 2000, 256, 0, stream>>>(X, ST, bn_g + l * 64, bn_b + l * 64, Tp);
    T = Tp;
  }

  k_out1<<<dim3(500, 8), dim3(16, 16), 0, stream>>>(SK, W1T, o1b, H1);
  k_out2<<<1500, 256, 0, stream>>>(H1, o2w, o2b, (float*)d_out);
}